// Round 15
// baseline (116.309 us; speedup 1.0000x reference)
//
#include <hip/hip_runtime.h>
#include <hip/hip_fp16.h>

// GCN 2-layer: x[N,128] -> (x@W1) agg -> relu -> (@W2) agg -> out[N,32]
// agg[i] = dinv[i] * sum_{j in in(i) + self} h[j]*dinv[j]  (+ bias)
// 2-kernel CSR build (k_part local sort -> k_bucket counting sort with
// wave-cooperative coalesced segment gather).
// gemm1 on MFMA f16. agg1 fused with gemm2 (64 nodes/block, 4-wave MFMA tile).
// agg2: 4 lanes/node, 8-deep gathers, unmasked full batches + masked tail.

#define IN_C 128
#define HID 64
#define OUTC 32
#define BSH 9            // bucket shift (512 nodes per bucket)
#define BSZ 512
#define NSLOT 256        // bucket slots (>= #buckets = 196)
#define EPB 8192         // edges per partition block
#define BSTRIDE 9216     // csr slots per bucket (mean 8192, +11 sigma pad)

typedef _Float16 half8 __attribute__((ext_vector_type(8)));
typedef float f32x4 __attribute__((ext_vector_type(4)));

static __host__ __device__ __forceinline__ size_t szt(int a) { return (size_t)a; }

// ---- pass 1: partition edges by bucket within each block -------------------
__global__ __launch_bounds__(256) void k_part(const int* __restrict__ src,
                                              const int* __restrict__ dst, int E,
                                              int* __restrict__ bedges,
                                              int* __restrict__ cnt,
                                              int* __restrict__ pre) {
  __shared__ int dbuf[EPB];     // 32 KB staged dst
  __shared__ int sorted[EPB];   // 32 KB bucket-grouped packed edges
  __shared__ int h[NSLOT];
  __shared__ int off[NSLOT];
  const int tid = threadIdx.x;
  h[tid] = 0;
  __syncthreads();
  const int e0 = blockIdx.x * EPB;
  const int n = min(EPB, E - e0);
  const int nv = n & ~3;
  for (int i = tid * 4; i < nv; i += 1024) {
    int4 d4 = *reinterpret_cast<const int4*>(&dst[e0 + i]);
    dbuf[i + 0] = d4.x; dbuf[i + 1] = d4.y;
    dbuf[i + 2] = d4.z; dbuf[i + 3] = d4.w;
    atomicAdd(&h[d4.x >> BSH], 1);
    atomicAdd(&h[d4.y >> BSH], 1);
    atomicAdd(&h[d4.z >> BSH], 1);
    atomicAdd(&h[d4.w >> BSH], 1);
  }
  for (int i = nv + tid; i < n; i += 256) {
    int d = dst[e0 + i];
    dbuf[i] = d;
    atomicAdd(&h[d >> BSH], 1);
  }
  __syncthreads();
  int v = h[tid];
  off[tid] = v;
  __syncthreads();
  for (int o = 1; o < 256; o <<= 1) {
    int w = (tid >= o) ? off[tid - o] : 0;
    __syncthreads();
    off[tid] += w;
    __syncthreads();
  }
  int excl = off[tid] - v;
  cnt[blockIdx.x * NSLOT + tid] = v;
  pre[blockIdx.x * NSLOT + tid] = excl;
  __syncthreads();
  off[tid] = excl;
  __syncthreads();
  for (int i = tid * 4; i < nv; i += 1024) {
    int4 s4 = *reinterpret_cast<const int4*>(&src[e0 + i]);
    int d0 = dbuf[i], d1 = dbuf[i + 1], d2 = dbuf[i + 2], d3 = dbuf[i + 3];
    int p0 = atomicAdd(&off[d0 >> BSH], 1);
    sorted[p0] = (s4.x << BSH) | (d0 & (BSZ - 1));
    int p1 = atomicAdd(&off[d1 >> BSH], 1);
    sorted[p1] = (s4.y << BSH) | (d1 & (BSZ - 1));
    int p2 = atomicAdd(&off[d2 >> BSH], 1);
    sorted[p2] = (s4.z << BSH) | (d2 & (BSZ - 1));
    int p3 = atomicAdd(&off[d3 >> BSH], 1);
    sorted[p3] = (s4.w << BSH) | (d3 & (BSZ - 1));
  }
  for (int i = nv + tid; i < n; i += 256) {
    int s = src[e0 + i], d = dbuf[i];
    int p = atomicAdd(&off[d >> BSH], 1);
    sorted[p] = (s << BSH) | (d & (BSZ - 1));
  }
  __syncthreads();
  for (int i = tid * 4; i < nv; i += 1024) {
    *reinterpret_cast<int4*>(&bedges[e0 + i]) =
        make_int4(sorted[i], sorted[i + 1], sorted[i + 2], sorted[i + 3]);
  }
  for (int i = nv + tid; i < n; i += 256) bedges[e0 + i] = sorted[i];
}

// ---- pass 2: per-bucket gather + counting sort -> csr/rd/dinv --------------
// segment gather is wave-cooperative: lanes stride one segment => coalesced.
__global__ __launch_bounds__(256) void k_bucket(const int* __restrict__ bedges,
                                                const int* __restrict__ cnt,
                                                const int* __restrict__ pre,
                                                int B, int E,
                                                int2* __restrict__ rd,
                                                float* __restrict__ dinv,
                                                int* __restrict__ csr, int N) {
  __shared__ int ebuf[BSTRIDE];
  __shared__ int obuf[BSTRIDE];
  __shared__ int h[BSZ];
  __shared__ int pfx[BSZ];
  __shared__ int c2[BSZ];
  __shared__ int sc[256];
  __shared__ int sgb[256];   // segment global base
  __shared__ int sdb[256];   // segment dest base in ebuf
  __shared__ int scn[256];   // segment count
  const int k = blockIdx.x;
  const int tid = threadIdx.x;
  h[tid] = 0; h[tid + 256] = 0;
  c2[tid] = 0; c2[tid + 256] = 0;
  int c = 0, so = 0;
  if (tid < B) {
    c = cnt[tid * NSLOT + k];
    so = pre[tid * NSLOT + k];
  }
  sc[tid] = c;
  __syncthreads();
  for (int o = 1; o < 256; o <<= 1) {
    int w = (tid >= o) ? sc[tid - o] : 0;
    __syncthreads();
    sc[tid] += w;
    __syncthreads();
  }
  sdb[tid] = sc[tid] - c;          // exclusive dest offset in ebuf
  sgb[tid] = tid * EPB + so;
  scn[tid] = c;
  __syncthreads();
  int total = sc[255];
  int nE = min(total, BSTRIDE);
  // wave-cooperative segment gather (coalesced within each segment)
  {
    const int wv = tid >> 6, ln = tid & 63;
    for (int s = wv; s < B; s += 4) {
      int sc_ = scn[s];
      int gb = sgb[s], db = sdb[s];
      for (int j = ln; j < sc_; j += 64) {
        int p = db + j;
        if (p < BSTRIDE) ebuf[p] = bedges[gb + j];
      }
    }
  }
  __syncthreads();
  for (int i = tid; i < nE; i += 256) atomicAdd(&h[ebuf[i] & (BSZ - 1)], 1);
  __syncthreads();
  int a0 = h[2 * tid], a1 = h[2 * tid + 1];
  int s = a0 + a1;
  sc[tid] = s;
  __syncthreads();
  for (int o = 1; o < 256; o <<= 1) {
    int w = (tid >= o) ? sc[tid - o] : 0;
    __syncthreads();
    sc[tid] += w;
    __syncthreads();
  }
  int ex = sc[tid] - s;
  pfx[2 * tid] = ex;
  pfx[2 * tid + 1] = ex + a0;
  __syncthreads();
  const int base = k * BSTRIDE;
  for (int i = tid; i < BSZ; i += 256) {
    int node = k * BSZ + i;
    if (node < N) {
      int dg = h[i];
      rd[node] = make_int2(base + pfx[i], dg);
      dinv[node] = rsqrtf((float)(dg + 1));
    }
  }
  for (int i = tid; i < nE; i += 256) {
    int e = ebuf[i];
    int l = e & (BSZ - 1);
    int p = pfx[l] + atomicAdd(&c2[l], 1);
    obuf[p] = e >> BSH;
  }
  __syncthreads();
  int nv = nE & ~3;
  for (int i = tid * 4; i < nv; i += 1024) {
    *reinterpret_cast<int4*>(&csr[base + i]) =
        make_int4(obuf[i], obuf[i + 1], obuf[i + 2], obuf[i + 3]);
  }
  for (int i = nv + tid; i < nE; i += 256) csr[base + i] = obuf[i];
}

// ---- GEMM1 (MFMA): h1s = x @ W1 * dinv[row]   [N,128]@[128,64] -> fp16 -----
__global__ __launch_bounds__(256) void k_gemm1(
    const float* __restrict__ x, const float* __restrict__ W1,
    const float* __restrict__ dinv, __half* __restrict__ h1s, int N) {
  __shared__ _Float16 bf[4 * 4 * 64 * 8];   // 16 KB
  const int tid = threadIdx.x;
  for (int idx = tid; idx < 128 * 64; idx += 256) {
    int k = idx >> 6, c = idx & 63;
    int kc = k >> 5, kk = k & 31;
    int chunk = kk >> 3, j = kk & 7;
    int ct = c >> 4, cl = c & 15;
    bf[(((kc * 4 + ct) * 64) + chunk * 16 + cl) * 8 + j] = (_Float16)W1[idx];
  }
  __syncthreads();

  const int lane = tid & 63, wave = tid >> 6;
  const int row0 = blockIdx.x * 64 + wave * 16;
  const int r_a = lane & 15;
  const int chk = lane >> 4;
  const int arow = min(row0 + r_a, N - 1);
  const float* xp = x + szt(arow) * IN_C + chk * 8;

  f32x4 acc[4];
  #pragma unroll
  for (int ct = 0; ct < 4; ++ct) acc[ct] = (f32x4){0.f, 0.f, 0.f, 0.f};

  #pragma unroll
  for (int kc = 0; kc < 4; ++kc) {
    float4 a0 = *reinterpret_cast<const float4*>(xp + kc * 32);
    float4 a1v = *reinterpret_cast<const float4*>(xp + kc * 32 + 4);
    half8 af;
    af[0] = (_Float16)a0.x;  af[1] = (_Float16)a0.y;
    af[2] = (_Float16)a0.z;  af[3] = (_Float16)a0.w;
    af[4] = (_Float16)a1v.x; af[5] = (_Float16)a1v.y;
    af[6] = (_Float16)a1v.z; af[7] = (_Float16)a1v.w;
    #pragma unroll
    for (int ct = 0; ct < 4; ++ct) {
      half8 bfrag = *reinterpret_cast<const half8*>(&bf[(((kc * 4 + ct) * 64) + lane) * 8]);
      acc[ct] = __builtin_amdgcn_mfma_f32_16x16x32_f16(af, bfrag, acc[ct], 0, 0, 0);
    }
  }
  #pragma unroll
  for (int r = 0; r < 4; ++r) {
    int drow = row0 + chk * 4 + r;
    if (drow < N) {
      float di = dinv[drow];
      #pragma unroll
      for (int ct = 0; ct < 4; ++ct)
        h1s[szt(drow) * HID + ct * 16 + r_a] = (__half)(acc[ct][r] * di);
    }
  }
}

// ---- agg1+gemm2 fused: 64 nodes/block, 2 nodes per 8-lane group ------------
__global__ __launch_bounds__(256) void k_agg1f(
    const __half* __restrict__ h1s, const int* __restrict__ csr,
    const int2* __restrict__ rd, const float* __restrict__ dinv,
    const float* __restrict__ b1, const float* __restrict__ W2,
    __half* __restrict__ h2s, int N) {
  __shared__ _Float16 bf[2 * 2 * 64 * 8];   // 4 KB W2 frags
  __shared__ _Float16 a1t[64 * 72];         // 9 KB a1 tile (64 rows)
  __shared__ float dinv_s[64];
  const int tid = threadIdx.x;

  for (int idx = tid; idx < 64 * 32; idx += 256) {
    int k = idx >> 5, c = idx & 31;
    int kc = k >> 5, kk = k & 31;
    int chunk = kk >> 3, j = kk & 7;
    int ct = c >> 4, cl = c & 15;
    bf[(((kc * 2 + ct) * 64) + chunk * 16 + cl) * 8 + j] = (_Float16)W2[idx];
  }

  // phase 1: gather-aggregate; each 8-lane group handles 2 nodes (nl, nl+32)
  const int l = tid & 7;
  const int g0 = (tid & 63) & ~7;
  const _Float16* hp = (const _Float16*)h1s;
  float4 bb0 = *reinterpret_cast<const float4*>(b1 + l * 8);
  float4 bb1 = *reinterpret_cast<const float4*>(b1 + l * 8 + 4);

  #pragma unroll
  for (int t = 0; t < 2; ++t) {
    const int nl = (tid >> 3) + t * 32;       // tile row 0..63
    const int node = blockIdx.x * 64 + nl;
    half8 o;
    #pragma unroll
    for (int q = 0; q < 8; ++q) o[q] = (_Float16)0.f;
    float di = 0.f;
    if (node < N) {
      half8 selfv = *reinterpret_cast<const half8*>(hp + szt(node) * HID + l * 8);
      float acc[8];
      #pragma unroll
      for (int q = 0; q < 8; ++q) acc[q] = (float)selfv[q];
      int2 v = rd[node];
      int base = v.x, cnt = v.y;
      if (cnt > 0) {
        int last = base + cnt - 1;
        int myidx = csr[min(base + l, last)];
        int j = 0;
        for (; j + 8 <= cnt; j += 8) {        // full batches, no masking
          int id[8];
          #pragma unroll
          for (int u = 0; u < 8; ++u) id[u] = __shfl(myidx, g0 + u);
          half8 gv[8];
          #pragma unroll
          for (int u = 0; u < 8; ++u)
            gv[u] = *reinterpret_cast<const half8*>(hp + szt(id[u]) * HID + l * 8);
          int jn = j + 8;
          if (jn < cnt) myidx = csr[min(base + jn + l, last)];
          #pragma unroll
          for (int u = 0; u < 8; ++u)
            #pragma unroll
            for (int q = 0; q < 8; ++q) acc[q] += (float)gv[u][q];
        }
        if (j < cnt) {                         // masked tail
          int id[8];
          #pragma unroll
          for (int u = 0; u < 8; ++u) id[u] = __shfl(myidx, g0 + u);
          half8 gv[8];
          #pragma unroll
          for (int u = 0; u < 8; ++u)
            gv[u] = *reinterpret_cast<const half8*>(hp + szt(id[u]) * HID + l * 8);
          #pragma unroll
          for (int u = 0; u < 8; ++u) {
            bool ok = (j + u) < cnt;
            #pragma unroll
            for (int q = 0; q < 8; ++q) acc[q] += ok ? (float)gv[u][q] : 0.0f;
          }
        }
      }
      di = dinv[node];
      o[0] = (_Float16)fmaxf(di * acc[0] + bb0.x, 0.f);
      o[1] = (_Float16)fmaxf(di * acc[1] + bb0.y, 0.f);
      o[2] = (_Float16)fmaxf(di * acc[2] + bb0.z, 0.f);
      o[3] = (_Float16)fmaxf(di * acc[3] + bb0.w, 0.f);
      o[4] = (_Float16)fmaxf(di * acc[4] + bb1.x, 0.f);
      o[5] = (_Float16)fmaxf(di * acc[5] + bb1.y, 0.f);
      o[6] = (_Float16)fmaxf(di * acc[6] + bb1.z, 0.f);
      o[7] = (_Float16)fmaxf(di * acc[7] + bb1.w, 0.f);
    }
    if (l == 0) dinv_s[nl] = di;
    *reinterpret_cast<half8*>(&a1t[nl * 72 + l * 8]) = o;
  }
  __syncthreads();

  // phase 2: MFMA matvec over the 64-row tile, all 4 waves (16 rows each)
  const int wave = tid >> 6;
  const int lane = tid & 63;
  const int r_a = lane & 15;
  const int chk = lane >> 4;
  const int tr = wave * 16 + r_a;
  f32x4 acc2[2];
  acc2[0] = (f32x4){0.f, 0.f, 0.f, 0.f};
  acc2[1] = (f32x4){0.f, 0.f, 0.f, 0.f};
  #pragma unroll
  for (int kc = 0; kc < 2; ++kc) {
    half8 af = *reinterpret_cast<const half8*>(&a1t[tr * 72 + chk * 8 + kc * 32]);
    #pragma unroll
    for (int ct = 0; ct < 2; ++ct) {
      half8 bfrag = *reinterpret_cast<const half8*>(&bf[(((kc * 2 + ct) * 64) + lane) * 8]);
      acc2[ct] = __builtin_amdgcn_mfma_f32_16x16x32_f16(af, bfrag, acc2[ct], 0, 0, 0);
    }
  }
  #pragma unroll
  for (int r = 0; r < 4; ++r) {
    int drow = wave * 16 + chk * 4 + r;
    int onode = blockIdx.x * 64 + drow;
    if (onode < N) {
      float di = dinv_s[drow];
      #pragma unroll
      for (int ct = 0; ct < 2; ++ct)
        h2s[szt(onode) * OUTC + ct * 16 + r_a] = (__half)(acc2[ct][r] * di);
    }
  }
}

// ---- agg2: 4 lanes/node, full batches unmasked, masked tail ----------------
__global__ __launch_bounds__(256) void k_agg2(
    const __half* __restrict__ h2s, const int* __restrict__ csr,
    const int2* __restrict__ rd, const float* __restrict__ dinv,
    const float* __restrict__ b2, float* __restrict__ out, int N) {
  const int tid = threadIdx.x;
  int node = blockIdx.x * 64 + (tid >> 2);
  if (node >= N) return;
  const int l = tid & 3;
  const int g0 = (tid & 63) & ~3;
  const _Float16* hp = (const _Float16*)h2s;

  half8 selfv = *reinterpret_cast<const half8*>(hp + szt(node) * OUTC + l * 8);
  float acc[8];
  #pragma unroll
  for (int q = 0; q < 8; ++q) acc[q] = (float)selfv[q];

  int2 v = rd[node];
  int base = v.x, cnt = v.y;
  if (cnt > 0) {
    int last = base + cnt - 1;
    int myA = csr[min(base + 2 * l, last)];
    int myB = csr[min(base + 2 * l + 1, last)];
    int j = 0;
    for (; j + 8 <= cnt; j += 8) {
      int id[8];
      #pragma unroll
      for (int u = 0; u < 4; ++u) {
        id[2 * u]     = __shfl(myA, g0 + u);
        id[2 * u + 1] = __shfl(myB, g0 + u);
      }
      half8 gv[8];
      #pragma unroll
      for (int u = 0; u < 8; ++u)
        gv[u] = *reinterpret_cast<const half8*>(hp + szt(id[u]) * OUTC + l * 8);
      int jn = j + 8;
      if (jn < cnt) {
        myA = csr[min(base + jn + 2 * l, last)];
        myB = csr[min(base + jn + 2 * l + 1, last)];
      }
      #pragma unroll
      for (int u = 0; u < 8; ++u)
        #pragma unroll
        for (int q = 0; q < 8; ++q) acc[q] += (float)gv[u][q];
    }
    if (j < cnt) {
      int id[8];
      #pragma unroll
      for (int u = 0; u < 4; ++u) {
        id[2 * u]     = __shfl(myA, g0 + u);
        id[2 * u + 1] = __shfl(myB, g0 + u);
      }
      half8 gv[8];
      #pragma unroll
      for (int u = 0; u < 8; ++u)
        gv[u] = *reinterpret_cast<const half8*>(hp + szt(id[u]) * OUTC + l * 8);
      #pragma unroll
      for (int u = 0; u < 8; ++u) {
        bool ok = (j + u) < cnt;
        #pragma unroll
        for (int q = 0; q < 8; ++q) acc[q] += ok ? (float)gv[u][q] : 0.0f;
      }
    }
  }
  float di = dinv[node];
  float4 bb0 = *reinterpret_cast<const float4*>(b2 + l * 8);
  float4 bb1 = *reinterpret_cast<const float4*>(b2 + l * 8 + 4);
  float4 o0, o1;
  o0.x = di * acc[0] + bb0.x; o0.y = di * acc[1] + bb0.y;
  o0.z = di * acc[2] + bb0.z; o0.w = di * acc[3] + bb0.w;
  o1.x = di * acc[4] + bb1.x; o1.y = di * acc[5] + bb1.y;
  o1.z = di * acc[6] + bb1.z; o1.w = di * acc[7] + bb1.w;
  float* op = out + szt(node) * OUTC + l * 8;
  *reinterpret_cast<float4*>(op) = o0;
  *reinterpret_cast<float4*>(op + 4) = o1;
}

extern "C" void kernel_launch(void* const* d_in, const int* in_sizes, int n_in,
                              void* d_out, int out_size, void* d_ws, size_t ws_size,
                              hipStream_t stream) {
  const float* x  = (const float*)d_in[0];
  const int*   ei = (const int*)d_in[1];
  const float* W1 = (const float*)d_in[2];
  const float* b1 = (const float*)d_in[3];
  const float* W2 = (const float*)d_in[4];
  const float* b2 = (const float*)d_in[5];
  float* out = (float*)d_out;

  const int N = in_sizes[0] / IN_C;
  const int E = in_sizes[1] / 2;
  const int* src = ei;
  const int* dst = ei + E;

  const int B   = (E + EPB - 1) / EPB;      // partition blocks (<= 256)
  const int NBK = (N + BSZ - 1) / BSZ;      // buckets (<= NSLOT)

  char* ws = (char*)d_ws;
  size_t off = 0;
  auto alloc = [&](size_t bytes) {
    off = (off + 255) & ~(size_t)255;
    void* p = ws + off;
    off += bytes;
    return p;
  };
  int*    cnt    = (int*)alloc(szt(B) * NSLOT * 4);
  int*    pre    = (int*)alloc(szt(B) * NSLOT * 4);
  int2*   rd     = (int2*)alloc(szt(N) * 8);
  float*  dinv   = (float*)alloc(szt(N) * 4);
  int*    bedges = (int*)alloc(szt(B) * EPB * 4);
  int*    csr    = (int*)alloc(szt(NBK) * BSTRIDE * 4);
  __half* h1s    = (__half*)alloc(szt(N) * HID * 2);
  __half* h2s    = (__half*)alloc(szt(N) * OUTC * 2);
  (void)ws_size;

  k_part<<<B, 256, 0, stream>>>(src, dst, E, bedges, cnt, pre);
  k_bucket<<<NBK, 256, 0, stream>>>(bedges, cnt, pre, B, E, rd, dinv, csr, N);
  k_gemm1<<<(N + 63) / 64, 256, 0, stream>>>(x, W1, dinv, h1s, N);
  k_agg1f<<<(N + 63) / 64, 256, 0, stream>>>(h1s, csr, rd, dinv, b1, W2, h2s, N);
  k_agg2<<<(N + 63) / 64, 256, 0, stream>>>(h2s, csr, rd, dinv, b2, out, N);
}

// Round 16
// 112.851 us; speedup vs baseline: 1.0306x; 1.0306x over previous
//
#include <hip/hip_runtime.h>
#include <hip/hip_fp16.h>

// GCN 2-layer: x[N,128] -> (x@W1) agg -> relu -> (@W2) agg -> out[N,32]
// agg[i] = dinv[i] * sum_{j in in(i) + self} h[j]*dinv[j]  (+ bias)
// 2-kernel CSR build (k_part local sort -> k_bucket counting sort).
// gemm1 on MFMA f16. agg1 fused with gemm2: 64 nodes/block (2 nodes per
// 8-lane group, load-balance smoothing), full 4-wave MFMA tile.
// agg2: 4 lanes/node, 8-deep gathers, unmasked full batches + masked tail.
// [Round 16: revert to round-14 best (112.9 us); r15 wave-coop gather was neutral/neg.]

#define IN_C 128
#define HID 64
#define OUTC 32
#define BSH 9            // bucket shift (512 nodes per bucket)
#define BSZ 512
#define NSLOT 256        // bucket slots (>= #buckets = 196)
#define EPB 8192         // edges per partition block
#define BSTRIDE 9216     // csr slots per bucket (mean 8192, +11 sigma pad)

typedef _Float16 half8 __attribute__((ext_vector_type(8)));
typedef float f32x4 __attribute__((ext_vector_type(4)));

static __host__ __device__ __forceinline__ size_t szt(int a) { return (size_t)a; }

// ---- pass 1: partition edges by bucket within each block -------------------
__global__ __launch_bounds__(256) void k_part(const int* __restrict__ src,
                                              const int* __restrict__ dst, int E,
                                              int* __restrict__ bedges,
                                              int* __restrict__ cnt,
                                              int* __restrict__ pre) {
  __shared__ int dbuf[EPB];     // 32 KB staged dst
  __shared__ int sorted[EPB];   // 32 KB bucket-grouped packed edges
  __shared__ int h[NSLOT];
  __shared__ int off[NSLOT];
  const int tid = threadIdx.x;
  h[tid] = 0;
  __syncthreads();
  const int e0 = blockIdx.x * EPB;
  const int n = min(EPB, E - e0);
  const int nv = n & ~3;
  for (int i = tid * 4; i < nv; i += 1024) {
    int4 d4 = *reinterpret_cast<const int4*>(&dst[e0 + i]);
    dbuf[i + 0] = d4.x; dbuf[i + 1] = d4.y;
    dbuf[i + 2] = d4.z; dbuf[i + 3] = d4.w;
    atomicAdd(&h[d4.x >> BSH], 1);
    atomicAdd(&h[d4.y >> BSH], 1);
    atomicAdd(&h[d4.z >> BSH], 1);
    atomicAdd(&h[d4.w >> BSH], 1);
  }
  for (int i = nv + tid; i < n; i += 256) {
    int d = dst[e0 + i];
    dbuf[i] = d;
    atomicAdd(&h[d >> BSH], 1);
  }
  __syncthreads();
  int v = h[tid];
  off[tid] = v;
  __syncthreads();
  for (int o = 1; o < 256; o <<= 1) {
    int w = (tid >= o) ? off[tid - o] : 0;
    __syncthreads();
    off[tid] += w;
    __syncthreads();
  }
  int excl = off[tid] - v;
  cnt[blockIdx.x * NSLOT + tid] = v;
  pre[blockIdx.x * NSLOT + tid] = excl;
  __syncthreads();
  off[tid] = excl;
  __syncthreads();
  for (int i = tid * 4; i < nv; i += 1024) {
    int4 s4 = *reinterpret_cast<const int4*>(&src[e0 + i]);
    int d0 = dbuf[i], d1 = dbuf[i + 1], d2 = dbuf[i + 2], d3 = dbuf[i + 3];
    int p0 = atomicAdd(&off[d0 >> BSH], 1);
    sorted[p0] = (s4.x << BSH) | (d0 & (BSZ - 1));
    int p1 = atomicAdd(&off[d1 >> BSH], 1);
    sorted[p1] = (s4.y << BSH) | (d1 & (BSZ - 1));
    int p2 = atomicAdd(&off[d2 >> BSH], 1);
    sorted[p2] = (s4.z << BSH) | (d2 & (BSZ - 1));
    int p3 = atomicAdd(&off[d3 >> BSH], 1);
    sorted[p3] = (s4.w << BSH) | (d3 & (BSZ - 1));
  }
  for (int i = nv + tid; i < n; i += 256) {
    int s = src[e0 + i], d = dbuf[i];
    int p = atomicAdd(&off[d >> BSH], 1);
    sorted[p] = (s << BSH) | (d & (BSZ - 1));
  }
  __syncthreads();
  for (int i = tid * 4; i < nv; i += 1024) {
    *reinterpret_cast<int4*>(&bedges[e0 + i]) =
        make_int4(sorted[i], sorted[i + 1], sorted[i + 2], sorted[i + 3]);
  }
  for (int i = nv + tid; i < n; i += 256) bedges[e0 + i] = sorted[i];
}

// ---- pass 2: per-bucket gather + counting sort -> csr/rd/dinv --------------
__global__ __launch_bounds__(256) void k_bucket(const int* __restrict__ bedges,
                                                const int* __restrict__ cnt,
                                                const int* __restrict__ pre,
                                                int B, int E,
                                                int2* __restrict__ rd,
                                                float* __restrict__ dinv,
                                                int* __restrict__ csr, int N) {
  __shared__ int ebuf[BSTRIDE];
  __shared__ int obuf[BSTRIDE];
  __shared__ int h[BSZ];
  __shared__ int pfx[BSZ];
  __shared__ int c2[BSZ];
  __shared__ int sc[256];
  __shared__ int dsto[256];
  const int k = blockIdx.x;
  const int tid = threadIdx.x;
  h[tid] = 0; h[tid + 256] = 0;
  c2[tid] = 0; c2[tid + 256] = 0;
  int c = 0, so = 0;
  if (tid < B) {
    c = cnt[tid * NSLOT + k];
    so = pre[tid * NSLOT + k];
  }
  sc[tid] = c;
  __syncthreads();
  for (int o = 1; o < 256; o <<= 1) {
    int w = (tid >= o) ? sc[tid - o] : 0;
    __syncthreads();
    sc[tid] += w;
    __syncthreads();
  }
  dsto[tid] = sc[tid] - c;
  __syncthreads();
  int total = sc[255];
  int nE = min(total, BSTRIDE);
  if (tid < B && c > 0) {
    int gbase = tid * EPB + so;
    int dbase = dsto[tid];
    for (int j = 0; j < c; ++j) {
      int p = dbase + j;
      if (p < BSTRIDE) ebuf[p] = bedges[gbase + j];
    }
  }
  __syncthreads();
  for (int i = tid; i < nE; i += 256) atomicAdd(&h[ebuf[i] & (BSZ - 1)], 1);
  __syncthreads();
  int a0 = h[2 * tid], a1 = h[2 * tid + 1];
  int s = a0 + a1;
  sc[tid] = s;
  __syncthreads();
  for (int o = 1; o < 256; o <<= 1) {
    int w = (tid >= o) ? sc[tid - o] : 0;
    __syncthreads();
    sc[tid] += w;
    __syncthreads();
  }
  int ex = sc[tid] - s;
  pfx[2 * tid] = ex;
  pfx[2 * tid + 1] = ex + a0;
  __syncthreads();
  const int base = k * BSTRIDE;
  for (int i = tid; i < BSZ; i += 256) {
    int node = k * BSZ + i;
    if (node < N) {
      int dg = h[i];
      rd[node] = make_int2(base + pfx[i], dg);
      dinv[node] = rsqrtf((float)(dg + 1));
    }
  }
  for (int i = tid; i < nE; i += 256) {
    int e = ebuf[i];
    int l = e & (BSZ - 1);
    int p = pfx[l] + atomicAdd(&c2[l], 1);
    obuf[p] = e >> BSH;
  }
  __syncthreads();
  int nv = nE & ~3;
  for (int i = tid * 4; i < nv; i += 1024) {
    *reinterpret_cast<int4*>(&csr[base + i]) =
        make_int4(obuf[i], obuf[i + 1], obuf[i + 2], obuf[i + 3]);
  }
  for (int i = nv + tid; i < nE; i += 256) csr[base + i] = obuf[i];
}

// ---- GEMM1 (MFMA): h1s = x @ W1 * dinv[row]   [N,128]@[128,64] -> fp16 -----
__global__ __launch_bounds__(256) void k_gemm1(
    const float* __restrict__ x, const float* __restrict__ W1,
    const float* __restrict__ dinv, __half* __restrict__ h1s, int N) {
  __shared__ _Float16 bf[4 * 4 * 64 * 8];   // 16 KB
  const int tid = threadIdx.x;
  for (int idx = tid; idx < 128 * 64; idx += 256) {
    int k = idx >> 6, c = idx & 63;
    int kc = k >> 5, kk = k & 31;
    int chunk = kk >> 3, j = kk & 7;
    int ct = c >> 4, cl = c & 15;
    bf[(((kc * 4 + ct) * 64) + chunk * 16 + cl) * 8 + j] = (_Float16)W1[idx];
  }
  __syncthreads();

  const int lane = tid & 63, wave = tid >> 6;
  const int row0 = blockIdx.x * 64 + wave * 16;
  const int r_a = lane & 15;
  const int chk = lane >> 4;
  const int arow = min(row0 + r_a, N - 1);
  const float* xp = x + szt(arow) * IN_C + chk * 8;

  f32x4 acc[4];
  #pragma unroll
  for (int ct = 0; ct < 4; ++ct) acc[ct] = (f32x4){0.f, 0.f, 0.f, 0.f};

  #pragma unroll
  for (int kc = 0; kc < 4; ++kc) {
    float4 a0 = *reinterpret_cast<const float4*>(xp + kc * 32);
    float4 a1v = *reinterpret_cast<const float4*>(xp + kc * 32 + 4);
    half8 af;
    af[0] = (_Float16)a0.x;  af[1] = (_Float16)a0.y;
    af[2] = (_Float16)a0.z;  af[3] = (_Float16)a0.w;
    af[4] = (_Float16)a1v.x; af[5] = (_Float16)a1v.y;
    af[6] = (_Float16)a1v.z; af[7] = (_Float16)a1v.w;
    #pragma unroll
    for (int ct = 0; ct < 4; ++ct) {
      half8 bfrag = *reinterpret_cast<const half8*>(&bf[(((kc * 4 + ct) * 64) + lane) * 8]);
      acc[ct] = __builtin_amdgcn_mfma_f32_16x16x32_f16(af, bfrag, acc[ct], 0, 0, 0);
    }
  }
  #pragma unroll
  for (int r = 0; r < 4; ++r) {
    int drow = row0 + chk * 4 + r;
    if (drow < N) {
      float di = dinv[drow];
      #pragma unroll
      for (int ct = 0; ct < 4; ++ct)
        h1s[szt(drow) * HID + ct * 16 + r_a] = (__half)(acc[ct][r] * di);
    }
  }
}

// ---- agg1+gemm2 fused: 64 nodes/block, 2 nodes per 8-lane group ------------
__global__ __launch_bounds__(256) void k_agg1f(
    const __half* __restrict__ h1s, const int* __restrict__ csr,
    const int2* __restrict__ rd, const float* __restrict__ dinv,
    const float* __restrict__ b1, const float* __restrict__ W2,
    __half* __restrict__ h2s, int N) {
  __shared__ _Float16 bf[2 * 2 * 64 * 8];   // 4 KB W2 frags
  __shared__ _Float16 a1t[64 * 72];         // 9 KB a1 tile (64 rows)
  __shared__ float dinv_s[64];
  const int tid = threadIdx.x;

  for (int idx = tid; idx < 64 * 32; idx += 256) {
    int k = idx >> 5, c = idx & 31;
    int kc = k >> 5, kk = k & 31;
    int chunk = kk >> 3, j = kk & 7;
    int ct = c >> 4, cl = c & 15;
    bf[(((kc * 2 + ct) * 64) + chunk * 16 + cl) * 8 + j] = (_Float16)W2[idx];
  }

  // phase 1: gather-aggregate; each 8-lane group handles 2 nodes (nl, nl+32)
  const int l = tid & 7;
  const int g0 = (tid & 63) & ~7;
  const _Float16* hp = (const _Float16*)h1s;
  float4 bb0 = *reinterpret_cast<const float4*>(b1 + l * 8);
  float4 bb1 = *reinterpret_cast<const float4*>(b1 + l * 8 + 4);

  #pragma unroll
  for (int t = 0; t < 2; ++t) {
    const int nl = (tid >> 3) + t * 32;       // tile row 0..63
    const int node = blockIdx.x * 64 + nl;
    half8 o;
    #pragma unroll
    for (int q = 0; q < 8; ++q) o[q] = (_Float16)0.f;
    float di = 0.f;
    if (node < N) {
      half8 selfv = *reinterpret_cast<const half8*>(hp + szt(node) * HID + l * 8);
      float acc[8];
      #pragma unroll
      for (int q = 0; q < 8; ++q) acc[q] = (float)selfv[q];
      int2 v = rd[node];
      int base = v.x, cnt = v.y;
      if (cnt > 0) {
        int last = base + cnt - 1;
        int myidx = csr[min(base + l, last)];
        int j = 0;
        for (; j + 8 <= cnt; j += 8) {        // full batches, no masking
          int id[8];
          #pragma unroll
          for (int u = 0; u < 8; ++u) id[u] = __shfl(myidx, g0 + u);
          half8 gv[8];
          #pragma unroll
          for (int u = 0; u < 8; ++u)
            gv[u] = *reinterpret_cast<const half8*>(hp + szt(id[u]) * HID + l * 8);
          int jn = j + 8;
          if (jn < cnt) myidx = csr[min(base + jn + l, last)];
          #pragma unroll
          for (int u = 0; u < 8; ++u)
            #pragma unroll
            for (int q = 0; q < 8; ++q) acc[q] += (float)gv[u][q];
        }
        if (j < cnt) {                         // masked tail
          int id[8];
          #pragma unroll
          for (int u = 0; u < 8; ++u) id[u] = __shfl(myidx, g0 + u);
          half8 gv[8];
          #pragma unroll
          for (int u = 0; u < 8; ++u)
            gv[u] = *reinterpret_cast<const half8*>(hp + szt(id[u]) * HID + l * 8);
          #pragma unroll
          for (int u = 0; u < 8; ++u) {
            bool ok = (j + u) < cnt;
            #pragma unroll
            for (int q = 0; q < 8; ++q) acc[q] += ok ? (float)gv[u][q] : 0.0f;
          }
        }
      }
      di = dinv[node];
      o[0] = (_Float16)fmaxf(di * acc[0] + bb0.x, 0.f);
      o[1] = (_Float16)fmaxf(di * acc[1] + bb0.y, 0.f);
      o[2] = (_Float16)fmaxf(di * acc[2] + bb0.z, 0.f);
      o[3] = (_Float16)fmaxf(di * acc[3] + bb0.w, 0.f);
      o[4] = (_Float16)fmaxf(di * acc[4] + bb1.x, 0.f);
      o[5] = (_Float16)fmaxf(di * acc[5] + bb1.y, 0.f);
      o[6] = (_Float16)fmaxf(di * acc[6] + bb1.z, 0.f);
      o[7] = (_Float16)fmaxf(di * acc[7] + bb1.w, 0.f);
    }
    if (l == 0) dinv_s[nl] = di;
    *reinterpret_cast<half8*>(&a1t[nl * 72 + l * 8]) = o;
  }
  __syncthreads();

  // phase 2: MFMA matvec over the 64-row tile, all 4 waves (16 rows each)
  const int wave = tid >> 6;
  const int lane = tid & 63;
  const int r_a = lane & 15;
  const int chk = lane >> 4;
  const int tr = wave * 16 + r_a;
  f32x4 acc2[2];
  acc2[0] = (f32x4){0.f, 0.f, 0.f, 0.f};
  acc2[1] = (f32x4){0.f, 0.f, 0.f, 0.f};
  #pragma unroll
  for (int kc = 0; kc < 2; ++kc) {
    half8 af = *reinterpret_cast<const half8*>(&a1t[tr * 72 + chk * 8 + kc * 32]);
    #pragma unroll
    for (int ct = 0; ct < 2; ++ct) {
      half8 bfrag = *reinterpret_cast<const half8*>(&bf[(((kc * 2 + ct) * 64) + lane) * 8]);
      acc2[ct] = __builtin_amdgcn_mfma_f32_16x16x32_f16(af, bfrag, acc2[ct], 0, 0, 0);
    }
  }
  #pragma unroll
  for (int r = 0; r < 4; ++r) {
    int drow = wave * 16 + chk * 4 + r;
    int onode = blockIdx.x * 64 + drow;
    if (onode < N) {
      float di = dinv_s[drow];
      #pragma unroll
      for (int ct = 0; ct < 2; ++ct)
        h2s[szt(onode) * OUTC + ct * 16 + r_a] = (__half)(acc2[ct][r] * di);
    }
  }
}

// ---- agg2: 4 lanes/node, full batches unmasked, masked tail ----------------
__global__ __launch_bounds__(256) void k_agg2(
    const __half* __restrict__ h2s, const int* __restrict__ csr,
    const int2* __restrict__ rd, const float* __restrict__ dinv,
    const float* __restrict__ b2, float* __restrict__ out, int N) {
  const int tid = threadIdx.x;
  int node = blockIdx.x * 64 + (tid >> 2);
  if (node >= N) return;
  const int l = tid & 3;
  const int g0 = (tid & 63) & ~3;
  const _Float16* hp = (const _Float16*)h2s;

  half8 selfv = *reinterpret_cast<const half8*>(hp + szt(node) * OUTC + l * 8);
  float acc[8];
  #pragma unroll
  for (int q = 0; q < 8; ++q) acc[q] = (float)selfv[q];

  int2 v = rd[node];
  int base = v.x, cnt = v.y;
  if (cnt > 0) {
    int last = base + cnt - 1;
    int myA = csr[min(base + 2 * l, last)];
    int myB = csr[min(base + 2 * l + 1, last)];
    int j = 0;
    for (; j + 8 <= cnt; j += 8) {
      int id[8];
      #pragma unroll
      for (int u = 0; u < 4; ++u) {
        id[2 * u]     = __shfl(myA, g0 + u);
        id[2 * u + 1] = __shfl(myB, g0 + u);
      }
      half8 gv[8];
      #pragma unroll
      for (int u = 0; u < 8; ++u)
        gv[u] = *reinterpret_cast<const half8*>(hp + szt(id[u]) * OUTC + l * 8);
      int jn = j + 8;
      if (jn < cnt) {
        myA = csr[min(base + jn + 2 * l, last)];
        myB = csr[min(base + jn + 2 * l + 1, last)];
      }
      #pragma unroll
      for (int u = 0; u < 8; ++u)
        #pragma unroll
        for (int q = 0; q < 8; ++q) acc[q] += (float)gv[u][q];
    }
    if (j < cnt) {
      int id[8];
      #pragma unroll
      for (int u = 0; u < 4; ++u) {
        id[2 * u]     = __shfl(myA, g0 + u);
        id[2 * u + 1] = __shfl(myB, g0 + u);
      }
      half8 gv[8];
      #pragma unroll
      for (int u = 0; u < 8; ++u)
        gv[u] = *reinterpret_cast<const half8*>(hp + szt(id[u]) * OUTC + l * 8);
      #pragma unroll
      for (int u = 0; u < 8; ++u) {
        bool ok = (j + u) < cnt;
        #pragma unroll
        for (int q = 0; q < 8; ++q) acc[q] += ok ? (float)gv[u][q] : 0.0f;
      }
    }
  }
  float di = dinv[node];
  float4 bb0 = *reinterpret_cast<const float4*>(b2 + l * 8);
  float4 bb1 = *reinterpret_cast<const float4*>(b2 + l * 8 + 4);
  float4 o0, o1;
  o0.x = di * acc[0] + bb0.x; o0.y = di * acc[1] + bb0.y;
  o0.z = di * acc[2] + bb0.z; o0.w = di * acc[3] + bb0.w;
  o1.x = di * acc[4] + bb1.x; o1.y = di * acc[5] + bb1.y;
  o1.z = di * acc[6] + bb1.z; o1.w = di * acc[7] + bb1.w;
  float* op = out + szt(node) * OUTC + l * 8;
  *reinterpret_cast<float4*>(op) = o0;
  *reinterpret_cast<float4*>(op + 4) = o1;
}

extern "C" void kernel_launch(void* const* d_in, const int* in_sizes, int n_in,
                              void* d_out, int out_size, void* d_ws, size_t ws_size,
                              hipStream_t stream) {
  const float* x  = (const float*)d_in[0];
  const int*   ei = (const int*)d_in[1];
  const float* W1 = (const float*)d_in[2];
  const float* b1 = (const float*)d_in[3];
  const float* W2 = (const float*)d_in[4];
  const float* b2 = (const float*)d_in[5];
  float* out = (float*)d_out;

  const int N = in_sizes[0] / IN_C;
  const int E = in_sizes[1] / 2;
  const int* src = ei;
  const int* dst = ei + E;

  const int B   = (E + EPB - 1) / EPB;      // partition blocks (<= 256)
  const int NBK = (N + BSZ - 1) / BSZ;      // buckets (<= NSLOT)

  char* ws = (char*)d_ws;
  size_t off = 0;
  auto alloc = [&](size_t bytes) {
    off = (off + 255) & ~(size_t)255;
    void* p = ws + off;
    off += bytes;
    return p;
  };
  int*    cnt    = (int*)alloc(szt(B) * NSLOT * 4);
  int*    pre    = (int*)alloc(szt(B) * NSLOT * 4);
  int2*   rd     = (int2*)alloc(szt(N) * 8);
  float*  dinv   = (float*)alloc(szt(N) * 4);
  int*    bedges = (int*)alloc(szt(B) * EPB * 4);
  int*    csr    = (int*)alloc(szt(NBK) * BSTRIDE * 4);
  __half* h1s    = (__half*)alloc(szt(N) * HID * 2);
  __half* h2s    = (__half*)alloc(szt(N) * OUTC * 2);
  (void)ws_size;

  k_part<<<B, 256, 0, stream>>>(src, dst, E, bedges, cnt, pre);
  k_bucket<<<NBK, 256, 0, stream>>>(bedges, cnt, pre, B, E, rd, dinv, csr, N);
  k_gemm1<<<(N + 63) / 64, 256, 0, stream>>>(x, W1, dinv, h1s, N);
  k_agg1f<<<(N + 63) / 64, 256, 0, stream>>>(h1s, csr, rd, dinv, b1, W2, h2s, N);
  k_agg2<<<(N + 63) / 64, 256, 0, stream>>>(h2s, csr, rd, dinv, b2, out, N);
}